// Round 1
// baseline (857.614 us; speedup 1.0000x reference)
//
#include <hip/hip_runtime.h>

#define N_NODES 50000
#define N_EDGES 800000
#define D_FEAT  128
#define EPS     1e-12f

// ---------------------------------------------------------------------------
// K1: inv_norm[n] = 1 / max(||feat[n]||, EPS)
// One wave (64 lanes) per node; each lane loads float2 (128 floats total).
// ---------------------------------------------------------------------------
__global__ void norm_kernel(const float* __restrict__ feat,
                            float* __restrict__ inv_norm) {
    const int lane = threadIdx.x & 63;
    const int node = blockIdx.x * (blockDim.x >> 6) + (threadIdx.x >> 6);
    if (node >= N_NODES) return;
    const float2* row = reinterpret_cast<const float2*>(feat + (size_t)node * D_FEAT);
    float2 v = row[lane];
    float s = v.x * v.x + v.y * v.y;
    #pragma unroll
    for (int off = 32; off > 0; off >>= 1)
        s += __shfl_xor(s, off, 64);
    if (lane == 0) {
        inv_norm[node] = 1.0f / fmaxf(sqrtf(s), EPS);
    }
}

// ---------------------------------------------------------------------------
// K2: per-edge unnormalized softmax weight
//   cos  = dot(feat[s], feat[d]) * inv_norm[s] * inv_norm[d]
//   e_exp[e] = exp(beta * cos)           (segment-max skipped: |beta*cos|<=|beta|, safe)
//   denom[dst] += e_exp  (atomic)
// One wave per edge.
// ---------------------------------------------------------------------------
__global__ void edge_kernel(const float* __restrict__ feat,
                            const float* __restrict__ inv_norm,
                            const int* __restrict__ src,
                            const int* __restrict__ dst,
                            const float* __restrict__ beta,
                            float* __restrict__ e_exp,
                            float* __restrict__ denom) {
    const int lane = threadIdx.x & 63;
    const int e = blockIdx.x * (blockDim.x >> 6) + (threadIdx.x >> 6);
    if (e >= N_EDGES) return;
    const int s = src[e];
    const int d = dst[e];
    const float2* rs = reinterpret_cast<const float2*>(feat + (size_t)s * D_FEAT);
    const float2* rd = reinterpret_cast<const float2*>(feat + (size_t)d * D_FEAT);
    float2 a = rs[lane];
    float2 b = rd[lane];
    float dot = a.x * b.x + a.y * b.y;
    #pragma unroll
    for (int off = 32; off > 0; off >>= 1)
        dot += __shfl_xor(dot, off, 64);
    if (lane == 0) {
        float ee = __expf(beta[0] * dot * inv_norm[s] * inv_norm[d]);
        e_exp[e] = ee;
        atomicAdd(&denom[d], ee);
    }
}

// ---------------------------------------------------------------------------
// K3: out[dst] += feat[src] * (e_exp / denom[dst])
// One wave per edge; each lane does 2 HW float atomics.
// ---------------------------------------------------------------------------
__global__ void agg_kernel(const float* __restrict__ feat,
                           const int* __restrict__ src,
                           const int* __restrict__ dst,
                           const float* __restrict__ e_exp,
                           const float* __restrict__ denom,
                           float* __restrict__ out) {
    const int lane = threadIdx.x & 63;
    const int e = blockIdx.x * (blockDim.x >> 6) + (threadIdx.x >> 6);
    if (e >= N_EDGES) return;
    const int s = src[e];
    const int d = dst[e];
    const float w = e_exp[e] / denom[d];
    const float2* rs = reinterpret_cast<const float2*>(feat + (size_t)s * D_FEAT);
    float2 a = rs[lane];
    float* od = out + (size_t)d * D_FEAT + lane * 2;
    unsafeAtomicAdd(od,     a.x * w);
    unsafeAtomicAdd(od + 1, a.y * w);
}

extern "C" void kernel_launch(void* const* d_in, const int* in_sizes, int n_in,
                              void* d_out, int out_size, void* d_ws, size_t ws_size,
                              hipStream_t stream) {
    const float* feat = (const float*)d_in[0];
    const float* beta = (const float*)d_in[1];
    const int*   src  = (const int*)d_in[2];
    const int*   dst  = (const int*)d_in[3];
    float* out = (float*)d_out;

    // workspace layout (floats): inv_norm[N] | denom[N] | e_exp[E]
    float* inv_norm = (float*)d_ws;
    float* denom    = inv_norm + N_NODES;
    float* e_exp    = denom + N_NODES;

    // zero accumulators (harness poisons buffers; atomics need clean zeros)
    hipMemsetAsync(out, 0, (size_t)N_NODES * D_FEAT * sizeof(float), stream);
    hipMemsetAsync(denom, 0, (size_t)N_NODES * sizeof(float), stream);

    const int WAVES_PER_BLOCK = 4;           // 256 threads
    const int BLOCK = WAVES_PER_BLOCK * 64;

    {
        int blocks = (N_NODES + WAVES_PER_BLOCK - 1) / WAVES_PER_BLOCK;
        norm_kernel<<<blocks, BLOCK, 0, stream>>>(feat, inv_norm);
    }
    {
        int blocks = (N_EDGES + WAVES_PER_BLOCK - 1) / WAVES_PER_BLOCK;
        edge_kernel<<<blocks, BLOCK, 0, stream>>>(feat, inv_norm, src, dst, beta,
                                                  e_exp, denom);
    }
    {
        int blocks = (N_EDGES + WAVES_PER_BLOCK - 1) / WAVES_PER_BLOCK;
        agg_kernel<<<blocks, BLOCK, 0, stream>>>(feat, src, dst, e_exp, denom, out);
    }
}

// Round 2
// 404.849 us; speedup vs baseline: 2.1184x; 2.1184x over previous
//
#include <hip/hip_runtime.h>

#define N_NODES 50000
#define N_EDGES 800000
#define D_FEAT  128
#define EPS     1e-12f
#define SCAN_T  1024

// ---------------------------------------------------------------------------
// K1: inv_norm[n] = 1 / max(||feat[n]||, EPS).  One wave per node.
// ---------------------------------------------------------------------------
__global__ void norm_kernel(const float* __restrict__ feat,
                            float* __restrict__ inv_norm) {
    const int lane = threadIdx.x & 63;
    const int node = blockIdx.x * (blockDim.x >> 6) + (threadIdx.x >> 6);
    if (node >= N_NODES) return;
    const float2* row = reinterpret_cast<const float2*>(feat + (size_t)node * D_FEAT);
    float2 v = row[lane];
    float s = v.x * v.x + v.y * v.y;
    #pragma unroll
    for (int off = 32; off > 0; off >>= 1)
        s += __shfl_xor(s, off, 64);
    if (lane == 0) {
        inv_norm[node] = 1.0f / fmaxf(sqrtf(s), EPS);
    }
}

// ---------------------------------------------------------------------------
// K2: counts[dst[e]]++ (grid-stride)
// ---------------------------------------------------------------------------
__global__ void count_kernel(const int* __restrict__ dst,
                             int* __restrict__ counts) {
    for (int e = blockIdx.x * blockDim.x + threadIdx.x; e < N_EDGES;
         e += gridDim.x * blockDim.x) {
        atomicAdd(&counts[dst[e]], 1);
    }
}

// ---------------------------------------------------------------------------
// K3: single-block exclusive scan over counts[N] -> offsets[N+1], cursor[N]
// ---------------------------------------------------------------------------
__global__ void scan_kernel(const int* __restrict__ counts,
                            int* __restrict__ offsets,
                            int* __restrict__ cursor) {
    __shared__ int sums[SCAN_T];
    const int t = threadIdx.x;
    const int chunk = (N_NODES + SCAN_T - 1) / SCAN_T;
    const int begin = t * chunk;
    const int end = min(begin + chunk, N_NODES);
    int s = 0;
    for (int i = begin; i < end; ++i) s += counts[i];
    sums[t] = s;
    __syncthreads();
    // Hillis-Steele inclusive scan
    for (int off = 1; off < SCAN_T; off <<= 1) {
        int v = (t >= off) ? sums[t - off] : 0;
        __syncthreads();
        if (t >= off) sums[t] += v;
        __syncthreads();
    }
    int pref = (t == 0) ? 0 : sums[t - 1];  // exclusive prefix of this chunk
    for (int i = begin; i < end; ++i) {
        offsets[i] = pref;
        cursor[i] = pref;
        pref += counts[i];
    }
    if (t == 0) offsets[N_NODES] = sums[SCAN_T - 1];
}

// ---------------------------------------------------------------------------
// K4: per-edge weight + scatter into dst-sorted arrays.  One wave per edge.
//   ee = exp(beta * dot(feat[s],feat[d]) * inv_norm[s] * inv_norm[d])
//   idx = cursor[d]++;  sorted_src[idx] = s; sorted_w[idx] = ee;
// ---------------------------------------------------------------------------
__global__ void edge_kernel(const float* __restrict__ feat,
                            const float* __restrict__ inv_norm,
                            const int* __restrict__ src,
                            const int* __restrict__ dst,
                            const float* __restrict__ beta,
                            int* __restrict__ cursor,
                            int* __restrict__ sorted_src,
                            float* __restrict__ sorted_w) {
    const int lane = threadIdx.x & 63;
    const int e = blockIdx.x * (blockDim.x >> 6) + (threadIdx.x >> 6);
    if (e >= N_EDGES) return;
    const int s = src[e];
    const int d = dst[e];
    const float2* rs = reinterpret_cast<const float2*>(feat + (size_t)s * D_FEAT);
    const float2* rd = reinterpret_cast<const float2*>(feat + (size_t)d * D_FEAT);
    float2 a = rs[lane];
    float2 b = rd[lane];
    float dot = a.x * b.x + a.y * b.y;
    #pragma unroll
    for (int off = 32; off > 0; off >>= 1)
        dot += __shfl_xor(dot, off, 64);
    if (lane == 0) {
        float ee = __expf(beta[0] * dot * inv_norm[s] * inv_norm[d]);
        int idx = atomicAdd(&cursor[d], 1);
        sorted_src[idx] = s;
        sorted_w[idx] = ee;
    }
}

// ---------------------------------------------------------------------------
// K5: wave-per-node aggregation, no atomics.
//   out[n] = (sum_k w_k * feat[src_k]) / (sum_k w_k)     (0 if no edges)
// ---------------------------------------------------------------------------
__global__ void agg_kernel(const float* __restrict__ feat,
                           const int* __restrict__ offsets,
                           const int* __restrict__ sorted_src,
                           const float* __restrict__ sorted_w,
                           float* __restrict__ out) {
    const int lane = threadIdx.x & 63;
    const int node = blockIdx.x * (blockDim.x >> 6) + (threadIdx.x >> 6);
    if (node >= N_NODES) return;
    const int kBeg = offsets[node];
    const int kEnd = offsets[node + 1];
    float2 acc = {0.0f, 0.0f};
    float denom = 0.0f;
    #pragma unroll 2
    for (int k = kBeg; k < kEnd; ++k) {
        const int s = sorted_src[k];       // broadcast across wave
        const float w = sorted_w[k];       // broadcast across wave
        const float2* rs = reinterpret_cast<const float2*>(feat + (size_t)s * D_FEAT);
        float2 a = rs[lane];
        acc.x += w * a.x;
        acc.y += w * a.y;
        denom += w;
    }
    const float scale = (kEnd > kBeg) ? (1.0f / denom) : 0.0f;
    float2* orow = reinterpret_cast<float2*>(out + (size_t)node * D_FEAT);
    orow[lane] = make_float2(acc.x * scale, acc.y * scale);
}

extern "C" void kernel_launch(void* const* d_in, const int* in_sizes, int n_in,
                              void* d_out, int out_size, void* d_ws, size_t ws_size,
                              hipStream_t stream) {
    const float* feat = (const float*)d_in[0];
    const float* beta = (const float*)d_in[1];
    const int*   src  = (const int*)d_in[2];
    const int*   dst  = (const int*)d_in[3];
    float* out = (float*)d_out;

    // ws layout: inv_norm[N] f32 | counts[N] i32 | offsets[N+1] i32 |
    //            cursor[N] i32 | sorted_src[E] i32 | sorted_w[E] f32
    float* inv_norm   = (float*)d_ws;
    int*   counts     = (int*)(inv_norm + N_NODES);
    int*   offsets    = counts + N_NODES;
    int*   cursor     = offsets + (N_NODES + 1);
    int*   sorted_src = cursor + N_NODES;
    float* sorted_w   = (float*)(sorted_src + N_EDGES);

    hipMemsetAsync(counts, 0, (size_t)N_NODES * sizeof(int), stream);

    const int WPB = 4;              // waves per block
    const int BLOCK = WPB * 64;     // 256 threads

    {
        int blocks = (N_NODES + WPB - 1) / WPB;
        norm_kernel<<<blocks, BLOCK, 0, stream>>>(feat, inv_norm);
    }
    count_kernel<<<512, 256, 0, stream>>>(dst, counts);
    scan_kernel<<<1, SCAN_T, 0, stream>>>(counts, offsets, cursor);
    {
        int blocks = (N_EDGES + WPB - 1) / WPB;
        edge_kernel<<<blocks, BLOCK, 0, stream>>>(feat, inv_norm, src, dst, beta,
                                                  cursor, sorted_src, sorted_w);
    }
    {
        int blocks = (N_NODES + WPB - 1) / WPB;
        agg_kernel<<<blocks, BLOCK, 0, stream>>>(feat, offsets, sorted_src,
                                                 sorted_w, out);
    }
}

// Round 3
// 314.463 us; speedup vs baseline: 2.7272x; 1.2874x over previous
//
#include <hip/hip_runtime.h>

#define N_NODES 50000
#define N_EDGES 800000
#define D_FEAT  128
#define EPS     1e-12f
#define SCAN_T  1024

// ---------------------------------------------------------------------------
// K1: inv_norm[n] = 1 / max(||feat[n]||, EPS).  One wave per node.
// ---------------------------------------------------------------------------
__global__ void norm_kernel(const float* __restrict__ feat,
                            float* __restrict__ inv_norm) {
    const int lane = threadIdx.x & 63;
    const int node = blockIdx.x * (blockDim.x >> 6) + (threadIdx.x >> 6);
    if (node >= N_NODES) return;
    const float2* row = reinterpret_cast<const float2*>(feat + (size_t)node * D_FEAT);
    float2 v = row[lane];
    float s = v.x * v.x + v.y * v.y;
    #pragma unroll
    for (int off = 32; off > 0; off >>= 1)
        s += __shfl_xor(s, off, 64);
    if (lane == 0) {
        inv_norm[node] = 1.0f / fmaxf(sqrtf(s), EPS);
    }
}

// ---------------------------------------------------------------------------
// K2: counts[dst[e]]++ (grid-stride, thread per edge)
// ---------------------------------------------------------------------------
__global__ void count_kernel(const int* __restrict__ dst,
                             int* __restrict__ counts) {
    for (int e = blockIdx.x * blockDim.x + threadIdx.x; e < N_EDGES;
         e += gridDim.x * blockDim.x) {
        atomicAdd(&counts[dst[e]], 1);
    }
}

// ---------------------------------------------------------------------------
// K3: single-block exclusive scan over counts[N] -> offsets[N+1], cursor[N]
// ---------------------------------------------------------------------------
__global__ void scan_kernel(const int* __restrict__ counts,
                            int* __restrict__ offsets,
                            int* __restrict__ cursor) {
    __shared__ int sums[SCAN_T];
    const int t = threadIdx.x;
    const int chunk = (N_NODES + SCAN_T - 1) / SCAN_T;
    const int begin = t * chunk;
    const int end = min(begin + chunk, N_NODES);
    int s = 0;
    for (int i = begin; i < end; ++i) s += counts[i];
    sums[t] = s;
    __syncthreads();
    for (int off = 1; off < SCAN_T; off <<= 1) {
        int v = (t >= off) ? sums[t - off] : 0;
        __syncthreads();
        if (t >= off) sums[t] += v;
        __syncthreads();
    }
    int pref = (t == 0) ? 0 : sums[t - 1];
    for (int i = begin; i < end; ++i) {
        offsets[i] = pref;
        cursor[i] = pref;
        pref += counts[i];
    }
    if (t == 0) offsets[N_NODES] = sums[SCAN_T - 1];
}

// ---------------------------------------------------------------------------
// K4: scatter src ids into dst-sorted order (thread per edge).
// ---------------------------------------------------------------------------
__global__ void scatter_kernel(const int* __restrict__ src,
                               const int* __restrict__ dst,
                               int* __restrict__ cursor,
                               int* __restrict__ sorted_src) {
    for (int e = blockIdx.x * blockDim.x + threadIdx.x; e < N_EDGES;
         e += gridDim.x * blockDim.x) {
        int idx = atomicAdd(&cursor[dst[e]], 1);
        sorted_src[idx] = src[e];
    }
}

// ---------------------------------------------------------------------------
// K5: fused per-node weight + aggregation. One wave per node, 2 edges/wave.
//   Half-wave h (32 lanes, float4 each) handles edge k0+h:
//     dot = <feat[s], feat[d]*inv_norm[d]>   (5-step shuffle reduce in half)
//     ee  = exp(beta * dot * inv_norm[s])
//     acc += ee * feat[s];  denom += ee
//   Final: combine halves via shfl_xor(32); out[d] = acc / denom (0 if empty).
// ---------------------------------------------------------------------------
__global__ void fused_agg(const float* __restrict__ feat,
                          const float* __restrict__ inv_norm,
                          const int* __restrict__ offsets,
                          const int* __restrict__ sorted_src,
                          const float* __restrict__ beta,
                          float* __restrict__ out) {
    const int lane = threadIdx.x & 63;
    const int half = lane >> 5;       // 0 or 1
    const int sub  = lane & 31;       // lane within half
    const int node = blockIdx.x * (blockDim.x >> 6) + (threadIdx.x >> 6);
    if (node >= N_NODES) return;

    const int kBeg = offsets[node];
    const int kEnd = offsets[node + 1];

    // dst row, scaled by its inv_norm (both halves load the same addresses)
    const float4* rd = reinterpret_cast<const float4*>(feat + (size_t)node * D_FEAT);
    float4 bd = rd[sub];
    const float bscale = inv_norm[node];
    bd.x *= bscale; bd.y *= bscale; bd.z *= bscale; bd.w *= bscale;
    const float betav = beta[0];

    float4 acc = {0.0f, 0.0f, 0.0f, 0.0f};
    float denom = 0.0f;

    for (int k0 = kBeg; k0 < kEnd; k0 += 2) {
        const int k = k0 + half;
        const bool valid = (k < kEnd);
        const int s = sorted_src[valid ? k : (kEnd - 1)];
        const float4* rs = reinterpret_cast<const float4*>(feat + (size_t)s * D_FEAT);
        float4 a = rs[sub];
        float dot = a.x * bd.x + a.y * bd.y + a.z * bd.z + a.w * bd.w;
        #pragma unroll
        for (int off = 16; off > 0; off >>= 1)     // stays within the half
            dot += __shfl_xor(dot, off, 64);
        const float ee = valid ? __expf(betav * dot * inv_norm[s]) : 0.0f;
        acc.x += ee * a.x;
        acc.y += ee * a.y;
        acc.z += ee * a.z;
        acc.w += ee * a.w;
        denom += ee;
    }

    // combine the two halves (same feature range, different edges)
    acc.x += __shfl_xor(acc.x, 32, 64);
    acc.y += __shfl_xor(acc.y, 32, 64);
    acc.z += __shfl_xor(acc.z, 32, 64);
    acc.w += __shfl_xor(acc.w, 32, 64);
    denom += __shfl_xor(denom, 32, 64);

    if (half == 0) {
        const float scale = (kEnd > kBeg) ? (1.0f / denom) : 0.0f;
        float4 r = make_float4(acc.x * scale, acc.y * scale,
                               acc.z * scale, acc.w * scale);
        reinterpret_cast<float4*>(out + (size_t)node * D_FEAT)[sub] = r;
    }
}

extern "C" void kernel_launch(void* const* d_in, const int* in_sizes, int n_in,
                              void* d_out, int out_size, void* d_ws, size_t ws_size,
                              hipStream_t stream) {
    const float* feat = (const float*)d_in[0];
    const float* beta = (const float*)d_in[1];
    const int*   src  = (const int*)d_in[2];
    const int*   dst  = (const int*)d_in[3];
    float* out = (float*)d_out;

    // ws layout: inv_norm[N] f32 | counts[N] i32 | offsets[N+1] i32 |
    //            cursor[N] i32 | sorted_src[E] i32
    float* inv_norm   = (float*)d_ws;
    int*   counts     = (int*)(inv_norm + N_NODES);
    int*   offsets    = counts + N_NODES;
    int*   cursor     = offsets + (N_NODES + 1);
    int*   sorted_src = cursor + N_NODES;

    hipMemsetAsync(counts, 0, (size_t)N_NODES * sizeof(int), stream);

    const int WPB = 4;              // waves per block
    const int BLOCK = WPB * 64;     // 256 threads

    {
        int blocks = (N_NODES + WPB - 1) / WPB;
        norm_kernel<<<blocks, BLOCK, 0, stream>>>(feat, inv_norm);
    }
    count_kernel<<<512, 256, 0, stream>>>(dst, counts);
    scan_kernel<<<1, SCAN_T, 0, stream>>>(counts, offsets, cursor);
    scatter_kernel<<<512, 256, 0, stream>>>(src, dst, cursor, sorted_src);
    {
        int blocks = (N_NODES + WPB - 1) / WPB;
        fused_agg<<<blocks, BLOCK, 0, stream>>>(feat, inv_norm, offsets,
                                                sorted_src, beta, out);
    }
}

// Round 4
// 210.323 us; speedup vs baseline: 4.0776x; 1.4951x over previous
//
#include <hip/hip_runtime.h>

#define N_NODES 50000
#define N_EDGES 800000
#define D_FEAT  128
#define EPS     1e-12f

#define S1_BLOCK 256
#define S1_TILE  1024                                   // 4 elems/thread
#define S1_NBLK  ((N_NODES + S1_TILE - 1) / S1_TILE)    // 49

// ---------------------------------------------------------------------------
// K1: inv_norm[n] = 1 / max(||feat[n]||, EPS).  One wave per node.
// ---------------------------------------------------------------------------
__global__ void norm_kernel(const float* __restrict__ feat,
                            float* __restrict__ inv_norm) {
    const int lane = threadIdx.x & 63;
    const int node = blockIdx.x * (blockDim.x >> 6) + (threadIdx.x >> 6);
    if (node >= N_NODES) return;
    const float2* row = reinterpret_cast<const float2*>(feat + (size_t)node * D_FEAT);
    float2 v = row[lane];
    float s = v.x * v.x + v.y * v.y;
    #pragma unroll
    for (int off = 32; off > 0; off >>= 1)
        s += __shfl_xor(s, off, 64);
    if (lane == 0) {
        inv_norm[node] = 1.0f / fmaxf(sqrtf(s), EPS);
    }
}

// ---------------------------------------------------------------------------
// K2: counts[dst[e]]++ (grid-stride, thread per edge)
// ---------------------------------------------------------------------------
__global__ void count_kernel(const int* __restrict__ dst,
                             int* __restrict__ counts) {
    for (int e = blockIdx.x * blockDim.x + threadIdx.x; e < N_EDGES;
         e += gridDim.x * blockDim.x) {
        atomicAdd(&counts[dst[e]], 1);
    }
}

// ---------------------------------------------------------------------------
// Scan phase 1: per-block scan of a 1024-elem tile (4/thread, int4).
// Writes per-element IN-BLOCK exclusive prefix into `offsets`, block total
// into block_sums[b].
// ---------------------------------------------------------------------------
__global__ void scan1_kernel(const int* __restrict__ counts,
                             int* __restrict__ offsets,
                             int* __restrict__ block_sums) {
    __shared__ int lds[S1_BLOCK];
    const int b = blockIdx.x, t = threadIdx.x;
    const int base = b * S1_TILE + t * 4;
    int v0 = 0, v1 = 0, v2 = 0, v3 = 0;
    if (base + 3 < N_NODES) {
        int4 v = *reinterpret_cast<const int4*>(counts + base);
        v0 = v.x; v1 = v.y; v2 = v.z; v3 = v.w;
    }
    const int tsum = v0 + v1 + v2 + v3;
    lds[t] = tsum;
    __syncthreads();
    // Hillis-Steele inclusive scan over 256 entries (8 steps)
    for (int off = 1; off < S1_BLOCK; off <<= 1) {
        int x = (t >= off) ? lds[t - off] : 0;
        __syncthreads();
        lds[t] += x;
        __syncthreads();
    }
    const int excl = lds[t] - tsum;
    if (t == S1_BLOCK - 1) block_sums[b] = lds[t];
    if (base + 3 < N_NODES) {
        int p0 = excl;
        int p1 = p0 + v0;
        int p2 = p1 + v1;
        int p3 = p2 + v2;
        *reinterpret_cast<int4*>(offsets + base) = make_int4(p0, p1, p2, p3);
    }
}

// ---------------------------------------------------------------------------
// Scan phase 2: one wave scans the 49 block sums in-place (-> exclusive
// block offsets) and writes the grand total to offsets[N_NODES].
// ---------------------------------------------------------------------------
__global__ void scan2_kernel(int* __restrict__ block_sums,
                             int* __restrict__ offsets) {
    const int lane = threadIdx.x;
    int v = (lane < S1_NBLK) ? block_sums[lane] : 0;
    int incl = v;
    #pragma unroll
    for (int off = 1; off < 64; off <<= 1) {
        int n = __shfl_up(incl, off, 64);
        if (lane >= off) incl += n;
    }
    if (lane < S1_NBLK) block_sums[lane] = incl - v;
    if (lane == 63) offsets[N_NODES] = incl;
}

// ---------------------------------------------------------------------------
// Scan phase 3: offsets[i] += block_offset[b]; cursor[i] = offsets[i].
// ---------------------------------------------------------------------------
__global__ void scan3_kernel(const int* __restrict__ block_sums,
                             int* __restrict__ offsets,
                             int* __restrict__ cursor) {
    const int b = blockIdx.x, t = threadIdx.x;
    const int base = b * S1_TILE + t * 4;
    if (base + 3 >= N_NODES) return;   // N_NODES % 4 == 0, so all-or-nothing
    const int boff = block_sums[b];
    int4 v = *reinterpret_cast<const int4*>(offsets + base);
    v.x += boff; v.y += boff; v.z += boff; v.w += boff;
    *reinterpret_cast<int4*>(offsets + base) = v;
    *reinterpret_cast<int4*>(cursor + base) = v;
}

// ---------------------------------------------------------------------------
// K4: scatter src ids into dst-sorted order (thread per edge).
// ---------------------------------------------------------------------------
__global__ void scatter_kernel(const int* __restrict__ src,
                               const int* __restrict__ dst,
                               int* __restrict__ cursor,
                               int* __restrict__ sorted_src) {
    for (int e = blockIdx.x * blockDim.x + threadIdx.x; e < N_EDGES;
         e += gridDim.x * blockDim.x) {
        int idx = atomicAdd(&cursor[dst[e]], 1);
        sorted_src[idx] = src[e];
    }
}

// ---------------------------------------------------------------------------
// K5: fused per-node weight + aggregation. One wave per node, 2 edges/wave.
// ---------------------------------------------------------------------------
__global__ void fused_agg(const float* __restrict__ feat,
                          const float* __restrict__ inv_norm,
                          const int* __restrict__ offsets,
                          const int* __restrict__ sorted_src,
                          const float* __restrict__ beta,
                          float* __restrict__ out) {
    const int lane = threadIdx.x & 63;
    const int half = lane >> 5;       // 0 or 1
    const int sub  = lane & 31;       // lane within half
    const int node = blockIdx.x * (blockDim.x >> 6) + (threadIdx.x >> 6);
    if (node >= N_NODES) return;

    const int kBeg = offsets[node];
    const int kEnd = offsets[node + 1];

    const float4* rd = reinterpret_cast<const float4*>(feat + (size_t)node * D_FEAT);
    float4 bd = rd[sub];
    const float bscale = inv_norm[node];
    bd.x *= bscale; bd.y *= bscale; bd.z *= bscale; bd.w *= bscale;
    const float betav = beta[0];

    float4 acc = {0.0f, 0.0f, 0.0f, 0.0f};
    float denom = 0.0f;

    for (int k0 = kBeg; k0 < kEnd; k0 += 2) {
        const int k = k0 + half;
        const bool valid = (k < kEnd);
        const int s = sorted_src[valid ? k : (kEnd - 1)];
        const float4* rs = reinterpret_cast<const float4*>(feat + (size_t)s * D_FEAT);
        float4 a = rs[sub];
        float dot = a.x * bd.x + a.y * bd.y + a.z * bd.z + a.w * bd.w;
        #pragma unroll
        for (int off = 16; off > 0; off >>= 1)
            dot += __shfl_xor(dot, off, 64);
        const float ee = valid ? __expf(betav * dot * inv_norm[s]) : 0.0f;
        acc.x += ee * a.x;
        acc.y += ee * a.y;
        acc.z += ee * a.z;
        acc.w += ee * a.w;
        denom += ee;
    }

    acc.x += __shfl_xor(acc.x, 32, 64);
    acc.y += __shfl_xor(acc.y, 32, 64);
    acc.z += __shfl_xor(acc.z, 32, 64);
    acc.w += __shfl_xor(acc.w, 32, 64);
    denom += __shfl_xor(denom, 32, 64);

    if (half == 0) {
        const float scale = (kEnd > kBeg) ? (1.0f / denom) : 0.0f;
        float4 r = make_float4(acc.x * scale, acc.y * scale,
                               acc.z * scale, acc.w * scale);
        reinterpret_cast<float4*>(out + (size_t)node * D_FEAT)[sub] = r;
    }
}

extern "C" void kernel_launch(void* const* d_in, const int* in_sizes, int n_in,
                              void* d_out, int out_size, void* d_ws, size_t ws_size,
                              hipStream_t stream) {
    const float* feat = (const float*)d_in[0];
    const float* beta = (const float*)d_in[1];
    const int*   src  = (const int*)d_in[2];
    const int*   dst  = (const int*)d_in[3];
    float* out = (float*)d_out;

    // ws layout: inv_norm[N] f32 | counts[N] i32 | offsets[N+1] i32 |
    //            cursor[N] i32 | block_sums[S1_NBLK] i32 | sorted_src[E] i32
    float* inv_norm   = (float*)d_ws;
    int*   counts     = (int*)(inv_norm + N_NODES);
    int*   offsets    = counts + N_NODES;
    int*   cursor     = offsets + (N_NODES + 1);
    int*   block_sums = cursor + N_NODES;
    int*   sorted_src = block_sums + S1_NBLK;

    hipMemsetAsync(counts, 0, (size_t)N_NODES * sizeof(int), stream);

    const int WPB = 4;              // waves per block
    const int BLOCK = WPB * 64;     // 256 threads

    {
        int blocks = (N_NODES + WPB - 1) / WPB;
        norm_kernel<<<blocks, BLOCK, 0, stream>>>(feat, inv_norm);
    }
    count_kernel<<<512, 256, 0, stream>>>(dst, counts);
    scan1_kernel<<<S1_NBLK, S1_BLOCK, 0, stream>>>(counts, offsets, block_sums);
    scan2_kernel<<<1, 64, 0, stream>>>(block_sums, offsets);
    scan3_kernel<<<S1_NBLK, S1_BLOCK, 0, stream>>>(block_sums, offsets, cursor);
    scatter_kernel<<<512, 256, 0, stream>>>(src, dst, cursor, sorted_src);
    {
        int blocks = (N_NODES + WPB - 1) / WPB;
        fused_agg<<<blocks, BLOCK, 0, stream>>>(feat, inv_norm, offsets,
                                                sorted_src, beta, out);
    }
}

// Round 5
// 171.352 us; speedup vs baseline: 5.0050x; 1.2274x over previous
//
#include <hip/hip_runtime.h>

#define N_NODES 50000
#define N_EDGES 800000
#define D_FEAT  128
#define EPS     1e-12f

#define S1_BLOCK 256
#define S1_TILE  1024                                   // 4 elems/thread
#define S1_NBLK  ((N_NODES + S1_TILE - 1) / S1_TILE)    // 49

__device__ __forceinline__ unsigned int f2bf(float x) {
    unsigned int u = __float_as_uint(x);
    return (u + 0x7FFFu + ((u >> 16) & 1u)) >> 16;      // RNE
}
__device__ __forceinline__ float bf_lo(unsigned int w) {
    return __uint_as_float(w << 16);
}
__device__ __forceinline__ float bf_hi(unsigned int w) {
    return __uint_as_float(w & 0xFFFF0000u);
}

// ---------------------------------------------------------------------------
// K1: per-node inv_norm + packed bf16 copy of feat; fused per-edge dst count.
// One wave per node (64 lanes x float2). Grid covers >= N_EDGES threads.
// ---------------------------------------------------------------------------
__global__ void norm_kernel(const float* __restrict__ feat,
                            float* __restrict__ inv_norm,
                            unsigned int* __restrict__ feat_bf,   // 64 words/row
                            const int* __restrict__ dst,
                            int* __restrict__ counts) {
    const int tid = blockIdx.x * blockDim.x + threadIdx.x;
    if (tid < N_EDGES) {
        atomicAdd(&counts[dst[tid]], 1);
    }
    const int lane = threadIdx.x & 63;
    const int node = blockIdx.x * (blockDim.x >> 6) + (threadIdx.x >> 6);
    if (node >= N_NODES) return;
    const float2* row = reinterpret_cast<const float2*>(feat + (size_t)node * D_FEAT);
    float2 v = row[lane];
    // pack: word w holds elements (2w, 2w+1)
    feat_bf[(size_t)node * 64 + lane] = (f2bf(v.y) << 16) | f2bf(v.x);
    float s = v.x * v.x + v.y * v.y;
    #pragma unroll
    for (int off = 32; off > 0; off >>= 1)
        s += __shfl_xor(s, off, 64);
    if (lane == 0) {
        inv_norm[node] = 1.0f / fmaxf(sqrtf(s), EPS);
    }
}

// ---------------------------------------------------------------------------
// Scan phase 1: per-block scan of a 1024-elem tile (4/thread, int4).
// ---------------------------------------------------------------------------
__global__ void scan1_kernel(const int* __restrict__ counts,
                             int* __restrict__ offsets,
                             int* __restrict__ block_sums) {
    __shared__ int lds[S1_BLOCK];
    const int b = blockIdx.x, t = threadIdx.x;
    const int base = b * S1_TILE + t * 4;
    int v0 = 0, v1 = 0, v2 = 0, v3 = 0;
    if (base + 3 < N_NODES) {
        int4 v = *reinterpret_cast<const int4*>(counts + base);
        v0 = v.x; v1 = v.y; v2 = v.z; v3 = v.w;
    }
    const int tsum = v0 + v1 + v2 + v3;
    lds[t] = tsum;
    __syncthreads();
    for (int off = 1; off < S1_BLOCK; off <<= 1) {
        int x = (t >= off) ? lds[t - off] : 0;
        __syncthreads();
        lds[t] += x;
        __syncthreads();
    }
    const int excl = lds[t] - tsum;
    if (t == S1_BLOCK - 1) block_sums[b] = lds[t];
    if (base + 3 < N_NODES) {
        int p0 = excl;
        *reinterpret_cast<int4*>(offsets + base) =
            make_int4(p0, p0 + v0, p0 + v0 + v1, p0 + v0 + v1 + v2);
    }
}

// ---------------------------------------------------------------------------
// Scan phase 2+3 fused: every block wave-scans the 49 block sums, adds its
// own block offset, writes offsets + cursor. Block 0 writes the grand total.
// ---------------------------------------------------------------------------
__global__ void scan23_kernel(const int* __restrict__ block_sums,
                              int* __restrict__ offsets,
                              int* __restrict__ cursor) {
    __shared__ int sh[2];   // [0]=this block's offset, [1]=grand total
    const int b = blockIdx.x, t = threadIdx.x;
    if (t < 64) {
        int v = (t < S1_NBLK) ? block_sums[t] : 0;
        int incl = v;
        #pragma unroll
        for (int off = 1; off < 64; off <<= 1) {
            int n = __shfl_up(incl, off, 64);
            if (t >= off) incl += n;
        }
        if (t == b) sh[0] = incl - v;
        if (t == S1_NBLK - 1) sh[1] = incl;
    }
    __syncthreads();
    const int base = b * S1_TILE + t * 4;
    if (base + 3 < N_NODES) {
        const int boff = sh[0];
        int4 v = *reinterpret_cast<const int4*>(offsets + base);
        v.x += boff; v.y += boff; v.z += boff; v.w += boff;
        *reinterpret_cast<int4*>(offsets + base) = v;
        *reinterpret_cast<int4*>(cursor + base) = v;
    }
    if (b == 0 && t == 0) offsets[N_NODES] = sh[1];
}

// ---------------------------------------------------------------------------
// K4: scatter src ids into dst-sorted order (thread per edge).
// ---------------------------------------------------------------------------
__global__ void scatter_kernel(const int* __restrict__ src,
                               const int* __restrict__ dst,
                               int* __restrict__ cursor,
                               int* __restrict__ sorted_src) {
    for (int e = blockIdx.x * blockDim.x + threadIdx.x; e < N_EDGES;
         e += gridDim.x * blockDim.x) {
        int idx = atomicAdd(&cursor[dst[e]], 1);
        sorted_src[idx] = src[e];
    }
}

// ---------------------------------------------------------------------------
// K5: fused per-node weight + aggregation over bf16 rows.
// One wave per node; 4 edges/iter via 16-lane groups (uint4 = 8 bf16 each).
// ---------------------------------------------------------------------------
__global__ void fused_agg(const unsigned int* __restrict__ feat_bf,
                          const float* __restrict__ inv_norm,
                          const int* __restrict__ offsets,
                          const int* __restrict__ sorted_src,
                          const float* __restrict__ beta,
                          float* __restrict__ out) {
    const int lane = threadIdx.x & 63;
    const int grp  = lane >> 4;       // 0..3  : edge slot
    const int sub  = lane & 15;       // lane within group
    const int node = blockIdx.x * (blockDim.x >> 6) + (threadIdx.x >> 6);
    if (node >= N_NODES) return;

    const int kBeg = offsets[node];
    const int kEnd = offsets[node + 1];

    // dst row (bf16 -> f32), scaled by inv_norm[dst]
    const uint4* rd = reinterpret_cast<const uint4*>(feat_bf + (size_t)node * 64);
    uint4 qd = rd[sub];
    const float bscale = inv_norm[node];
    float bd[8];
    bd[0] = bf_lo(qd.x) * bscale; bd[1] = bf_hi(qd.x) * bscale;
    bd[2] = bf_lo(qd.y) * bscale; bd[3] = bf_hi(qd.y) * bscale;
    bd[4] = bf_lo(qd.z) * bscale; bd[5] = bf_hi(qd.z) * bscale;
    bd[6] = bf_lo(qd.w) * bscale; bd[7] = bf_hi(qd.w) * bscale;
    const float betav = beta[0];

    float acc[8] = {0, 0, 0, 0, 0, 0, 0, 0};
    float denom = 0.0f;

    for (int k0 = kBeg; k0 < kEnd; k0 += 4) {
        const int k = k0 + grp;
        const bool valid = (k < kEnd);
        const int s = sorted_src[valid ? k : (kEnd - 1)];
        const uint4* rs = reinterpret_cast<const uint4*>(feat_bf + (size_t)s * 64);
        uint4 q = rs[sub];
        float a[8];
        a[0] = bf_lo(q.x); a[1] = bf_hi(q.x);
        a[2] = bf_lo(q.y); a[3] = bf_hi(q.y);
        a[4] = bf_lo(q.z); a[5] = bf_hi(q.z);
        a[6] = bf_lo(q.w); a[7] = bf_hi(q.w);
        float dot = 0.0f;
        #pragma unroll
        for (int j = 0; j < 8; ++j) dot += a[j] * bd[j];
        #pragma unroll
        for (int off = 8; off > 0; off >>= 1)      // reduce within 16-lane group
            dot += __shfl_xor(dot, off, 64);
        const float ee = valid ? __expf(betav * dot * inv_norm[s]) : 0.0f;
        #pragma unroll
        for (int j = 0; j < 8; ++j) acc[j] += ee * a[j];
        denom += ee;
    }

    // combine the 4 groups (same feature slots, different edges)
    #pragma unroll
    for (int j = 0; j < 8; ++j) {
        acc[j] += __shfl_xor(acc[j], 16, 64);
        acc[j] += __shfl_xor(acc[j], 32, 64);
    }
    denom += __shfl_xor(denom, 16, 64);
    denom += __shfl_xor(denom, 32, 64);

    if (grp == 0) {
        const float scale = (kEnd > kBeg) ? (1.0f / denom) : 0.0f;
        float4* orow = reinterpret_cast<float4*>(out + (size_t)node * D_FEAT);
        orow[2 * sub] = make_float4(acc[0] * scale, acc[1] * scale,
                                    acc[2] * scale, acc[3] * scale);
        orow[2 * sub + 1] = make_float4(acc[4] * scale, acc[5] * scale,
                                        acc[6] * scale, acc[7] * scale);
    }
}

extern "C" void kernel_launch(void* const* d_in, const int* in_sizes, int n_in,
                              void* d_out, int out_size, void* d_ws, size_t ws_size,
                              hipStream_t stream) {
    const float* feat = (const float*)d_in[0];
    const float* beta = (const float*)d_in[1];
    const int*   src  = (const int*)d_in[2];
    const int*   dst  = (const int*)d_in[3];
    float* out = (float*)d_out;

    // ws layout: inv_norm[N] f32 | counts[N] i32 | offsets[N+1] i32 |
    //            cursor[N] i32 | block_sums[49] i32 | sorted_src[E] i32 |
    //            feat_bf[N*64] u32  (12.8 MB)
    float*        inv_norm   = (float*)d_ws;
    int*          counts     = (int*)(inv_norm + N_NODES);
    int*          offsets    = counts + N_NODES;
    int*          cursor     = offsets + (N_NODES + 1);
    int*          block_sums = cursor + N_NODES;
    int*          sorted_src = block_sums + S1_NBLK;
    unsigned int* feat_bf    = (unsigned int*)(sorted_src + N_EDGES);

    hipMemsetAsync(counts, 0, (size_t)N_NODES * sizeof(int), stream);

    const int WPB = 4;              // waves per block
    const int BLOCK = WPB * 64;     // 256 threads

    {
        int blocks = (N_NODES + WPB - 1) / WPB;   // 12500 blocks -> 3.2M threads
        norm_kernel<<<blocks, BLOCK, 0, stream>>>(feat, inv_norm, feat_bf,
                                                  dst, counts);
    }
    scan1_kernel<<<S1_NBLK, S1_BLOCK, 0, stream>>>(counts, offsets, block_sums);
    scan23_kernel<<<S1_NBLK, S1_BLOCK, 0, stream>>>(block_sums, offsets, cursor);
    scatter_kernel<<<512, 256, 0, stream>>>(src, dst, cursor, sorted_src);
    {
        int blocks = (N_NODES + WPB - 1) / WPB;
        fused_agg<<<blocks, BLOCK, 0, stream>>>(feat_bf, inv_norm, offsets,
                                                sorted_src, beta, out);
    }
}

// Round 6
// 121.309 us; speedup vs baseline: 7.0697x; 1.4125x over previous
//
#include <hip/hip_runtime.h>

#define N_NODES 50000
#define N_EDGES 800000
#define D_FEAT  128
#define EPS     1e-12f

#define S1_BLOCK 256
#define S1_TILE  1024                                   // 4 elems/thread
#define S1_NBLK  ((N_NODES + S1_TILE - 1) / S1_TILE)    // 49

__device__ __forceinline__ unsigned int f2bf(float x) {
    unsigned int u = __float_as_uint(x);
    return (u + 0x7FFFu + ((u >> 16) & 1u)) >> 16;      // RNE
}
__device__ __forceinline__ float bf_lo(unsigned int w) {
    return __uint_as_float(w << 16);
}
__device__ __forceinline__ float bf_hi(unsigned int w) {
    return __uint_as_float(w & 0xFFFF0000u);
}

// ---------------------------------------------------------------------------
// K1: per-node inv_norm + packed bf16 copy of feat; fused per-edge dst count
// that ALSO records each edge's within-node rank (atomic return value).
// ---------------------------------------------------------------------------
__global__ void norm_kernel(const float* __restrict__ feat,
                            float* __restrict__ inv_norm,
                            unsigned int* __restrict__ feat_bf,   // 64 words/row
                            const int* __restrict__ dst,
                            int* __restrict__ counts,
                            int* __restrict__ rank) {
    const int tid = blockIdx.x * blockDim.x + threadIdx.x;
    if (tid < N_EDGES) {
        rank[tid] = atomicAdd(&counts[dst[tid]], 1);
    }
    const int lane = threadIdx.x & 63;
    const int node = blockIdx.x * (blockDim.x >> 6) + (threadIdx.x >> 6);
    if (node >= N_NODES) return;
    const float2* row = reinterpret_cast<const float2*>(feat + (size_t)node * D_FEAT);
    float2 v = row[lane];
    feat_bf[(size_t)node * 64 + lane] = (f2bf(v.y) << 16) | f2bf(v.x);
    float s = v.x * v.x + v.y * v.y;
    #pragma unroll
    for (int off = 32; off > 0; off >>= 1)
        s += __shfl_xor(s, off, 64);
    if (lane == 0) {
        inv_norm[node] = 1.0f / fmaxf(sqrtf(s), EPS);
    }
}

// ---------------------------------------------------------------------------
// Scan phase 1: per-block scan of a 1024-elem tile (4/thread, int4).
// ---------------------------------------------------------------------------
__global__ void scan1_kernel(const int* __restrict__ counts,
                             int* __restrict__ offsets,
                             int* __restrict__ block_sums) {
    __shared__ int lds[S1_BLOCK];
    const int b = blockIdx.x, t = threadIdx.x;
    const int base = b * S1_TILE + t * 4;
    int v0 = 0, v1 = 0, v2 = 0, v3 = 0;
    if (base + 3 < N_NODES) {
        int4 v = *reinterpret_cast<const int4*>(counts + base);
        v0 = v.x; v1 = v.y; v2 = v.z; v3 = v.w;
    }
    const int tsum = v0 + v1 + v2 + v3;
    lds[t] = tsum;
    __syncthreads();
    for (int off = 1; off < S1_BLOCK; off <<= 1) {
        int x = (t >= off) ? lds[t - off] : 0;
        __syncthreads();
        lds[t] += x;
        __syncthreads();
    }
    const int excl = lds[t] - tsum;
    if (t == S1_BLOCK - 1) block_sums[b] = lds[t];
    if (base + 3 < N_NODES) {
        int p0 = excl;
        *reinterpret_cast<int4*>(offsets + base) =
            make_int4(p0, p0 + v0, p0 + v0 + v1, p0 + v0 + v1 + v2);
    }
}

// ---------------------------------------------------------------------------
// Scan phase 2+3 fused: every block wave-scans the 49 block sums, adds its
// own block offset, writes offsets. Block 0 writes the grand total.
// ---------------------------------------------------------------------------
__global__ void scan23_kernel(const int* __restrict__ block_sums,
                              int* __restrict__ offsets) {
    __shared__ int sh[2];
    const int b = blockIdx.x, t = threadIdx.x;
    if (t < 64) {
        int v = (t < S1_NBLK) ? block_sums[t] : 0;
        int incl = v;
        #pragma unroll
        for (int off = 1; off < 64; off <<= 1) {
            int n = __shfl_up(incl, off, 64);
            if (t >= off) incl += n;
        }
        if (t == b) sh[0] = incl - v;
        if (t == S1_NBLK - 1) sh[1] = incl;
    }
    __syncthreads();
    const int base = b * S1_TILE + t * 4;
    if (base + 3 < N_NODES) {
        const int boff = sh[0];
        int4 v = *reinterpret_cast<const int4*>(offsets + base);
        v.x += boff; v.y += boff; v.z += boff; v.w += boff;
        *reinterpret_cast<int4*>(offsets + base) = v;
    }
    if (b == 0 && t == 0) offsets[N_NODES] = sh[1];
}

// ---------------------------------------------------------------------------
// K4: atomic-free scatter: sorted_src[offsets[dst[e]] + rank[e]] = src[e].
// One thread per edge, full occupancy.
// ---------------------------------------------------------------------------
__global__ void scatter_kernel(const int* __restrict__ src,
                               const int* __restrict__ dst,
                               const int* __restrict__ offsets,
                               const int* __restrict__ rank,
                               int* __restrict__ sorted_src) {
    const int e = blockIdx.x * blockDim.x + threadIdx.x;
    if (e >= N_EDGES) return;
    sorted_src[offsets[dst[e]] + rank[e]] = src[e];
}

// ---------------------------------------------------------------------------
// K5: fused per-node weight + aggregation over bf16 rows.
// One wave per node; 4 edges/iter via 16-lane groups (uint4 = 8 bf16 each).
// ---------------------------------------------------------------------------
__global__ void fused_agg(const unsigned int* __restrict__ feat_bf,
                          const float* __restrict__ inv_norm,
                          const int* __restrict__ offsets,
                          const int* __restrict__ sorted_src,
                          const float* __restrict__ beta,
                          float* __restrict__ out) {
    const int lane = threadIdx.x & 63;
    const int grp  = lane >> 4;       // 0..3  : edge slot
    const int sub  = lane & 15;       // lane within group
    const int node = blockIdx.x * (blockDim.x >> 6) + (threadIdx.x >> 6);
    if (node >= N_NODES) return;

    const int kBeg = offsets[node];
    const int kEnd = offsets[node + 1];

    const uint4* rd = reinterpret_cast<const uint4*>(feat_bf + (size_t)node * 64);
    uint4 qd = rd[sub];
    const float bscale = inv_norm[node];
    float bd[8];
    bd[0] = bf_lo(qd.x) * bscale; bd[1] = bf_hi(qd.x) * bscale;
    bd[2] = bf_lo(qd.y) * bscale; bd[3] = bf_hi(qd.y) * bscale;
    bd[4] = bf_lo(qd.z) * bscale; bd[5] = bf_hi(qd.z) * bscale;
    bd[6] = bf_lo(qd.w) * bscale; bd[7] = bf_hi(qd.w) * bscale;
    const float betav = beta[0];

    float acc[8] = {0, 0, 0, 0, 0, 0, 0, 0};
    float denom = 0.0f;

    for (int k0 = kBeg; k0 < kEnd; k0 += 4) {
        const int k = k0 + grp;
        const bool valid = (k < kEnd);
        const int s = sorted_src[valid ? k : (kEnd - 1)];
        const uint4* rs = reinterpret_cast<const uint4*>(feat_bf + (size_t)s * 64);
        uint4 q = rs[sub];
        float a[8];
        a[0] = bf_lo(q.x); a[1] = bf_hi(q.x);
        a[2] = bf_lo(q.y); a[3] = bf_hi(q.y);
        a[4] = bf_lo(q.z); a[5] = bf_hi(q.z);
        a[6] = bf_lo(q.w); a[7] = bf_hi(q.w);
        float dot = 0.0f;
        #pragma unroll
        for (int j = 0; j < 8; ++j) dot += a[j] * bd[j];
        #pragma unroll
        for (int off = 8; off > 0; off >>= 1)
            dot += __shfl_xor(dot, off, 64);
        const float ee = valid ? __expf(betav * dot * inv_norm[s]) : 0.0f;
        #pragma unroll
        for (int j = 0; j < 8; ++j) acc[j] += ee * a[j];
        denom += ee;
    }

    #pragma unroll
    for (int j = 0; j < 8; ++j) {
        acc[j] += __shfl_xor(acc[j], 16, 64);
        acc[j] += __shfl_xor(acc[j], 32, 64);
    }
    denom += __shfl_xor(denom, 16, 64);
    denom += __shfl_xor(denom, 32, 64);

    if (grp == 0) {
        const float scale = (kEnd > kBeg) ? (1.0f / denom) : 0.0f;
        float4* orow = reinterpret_cast<float4*>(out + (size_t)node * D_FEAT);
        orow[2 * sub] = make_float4(acc[0] * scale, acc[1] * scale,
                                    acc[2] * scale, acc[3] * scale);
        orow[2 * sub + 1] = make_float4(acc[4] * scale, acc[5] * scale,
                                        acc[6] * scale, acc[7] * scale);
    }
}

extern "C" void kernel_launch(void* const* d_in, const int* in_sizes, int n_in,
                              void* d_out, int out_size, void* d_ws, size_t ws_size,
                              hipStream_t stream) {
    const float* feat = (const float*)d_in[0];
    const float* beta = (const float*)d_in[1];
    const int*   src  = (const int*)d_in[2];
    const int*   dst  = (const int*)d_in[3];
    float* out = (float*)d_out;

    // ws layout: inv_norm[N] f32 | counts[N] i32 | offsets[N+1] i32 |
    //            block_sums[49] i32 | rank[E] i32 | sorted_src[E] i32 |
    //            feat_bf[N*64] u32  (12.8 MB)
    float*        inv_norm   = (float*)d_ws;
    int*          counts     = (int*)(inv_norm + N_NODES);
    int*          offsets    = counts + N_NODES;
    int*          block_sums = offsets + (N_NODES + 1);
    int*          rank       = block_sums + S1_NBLK;
    int*          sorted_src = rank + N_EDGES;
    unsigned int* feat_bf    = (unsigned int*)(sorted_src + N_EDGES);

    hipMemsetAsync(counts, 0, (size_t)N_NODES * sizeof(int), stream);

    const int WPB = 4;              // waves per block
    const int BLOCK = WPB * 64;     // 256 threads

    {
        int blocks = (N_NODES + WPB - 1) / WPB;   // 12500 blocks -> 3.2M threads
        norm_kernel<<<blocks, BLOCK, 0, stream>>>(feat, inv_norm, feat_bf,
                                                  dst, counts, rank);
    }
    scan1_kernel<<<S1_NBLK, S1_BLOCK, 0, stream>>>(counts, offsets, block_sums);
    scan23_kernel<<<S1_NBLK, S1_BLOCK, 0, stream>>>(block_sums, offsets);
    {
        int blocks = (N_EDGES + 255) / 256;       // one thread per edge
        scatter_kernel<<<blocks, 256, 0, stream>>>(src, dst, offsets, rank,
                                                   sorted_src);
    }
    {
        int blocks = (N_NODES + WPB - 1) / WPB;
        fused_agg<<<blocks, BLOCK, 0, stream>>>(feat_bf, inv_norm, offsets,
                                                sorted_src, beta, out);
    }
}